// Round 8
// baseline (141.692 us; speedup 1.0000x reference)
//
#include <hip/hip_runtime.h>
#include <stdint.h>

#define V 257
#define NB 64
#define L 1024
#define ZERO_STATE 257   // table slot for the all-zero prev vector
#define NSTATE 258
#define CHUNKS 32        // C
#define CLEN 32          // K ; C*K == L
#define VECS_PER_CHUNK 2056   // 32*257/4, exact; chunk base is f32x4-aligned

typedef float f32x4 __attribute__((ext_vector_type(4)));

// transition: state p + input index x -> next state (== output index;
// ZERO_STATE means "output is the all-zero vector").
__device__ __forceinline__ int gstep(const uint32_t* __restrict__ tbl, int p, int x) {
    uint32_t e = tbl[p];
    int ia  = (int)(e >> 16);
    int loc = (int)(e & 0xffff);
    int s = x - loc;               // (-257, 257)
    s += (s >> 31) & V;            // mod V -> [0,256]
    int n = s * ia;                // <= 65536
    int m = (n & 255) - (n >> 8);  // 256 == -1 (mod 257) fold -> [-256,255]
    m += (m >> 31) & V;            // -> [0,256]
    return (ia == 0) ? ZERO_STATE : m;
}

// K1: per-state transition table. entry = loc | ia<<16; ia==0 encodes zero-vector out.
__global__ void table_k(const float* __restrict__ W, const float* __restrict__ bias,
                        const int* __restrict__ inv_table, uint32_t* __restrict__ gtable) {
    int lane = threadIdx.x;
    int p = blockIdx.x;              // 257 = zero state (net = bias only)
    const float* wrow = (p < V) ? (W + (size_t)p * (2 * V)) : nullptr;
    float bestL = -INFINITY; int idxL = 0;
    float bestS = -INFINITY; int idxS = 0;
    for (int j = lane; j < V; j += 64) {
        float vl = wrow ? (wrow[j] + bias[j]) : bias[j];
        float vs = wrow ? (wrow[V + j] + bias[V + j]) : bias[V + j];
        if (vl > bestL) { bestL = vl; idxL = j; }   // ascending j => first-max kept
        if (vs > bestS) { bestS = vs; idxS = j; }
    }
    for (int off = 32; off >= 1; off >>= 1) {       // wave-64 first-index argmax reduce
        float oL = __shfl_down(bestL, off); int oiL = __shfl_down(idxL, off);
        float oS = __shfl_down(bestS, off); int oiS = __shfl_down(idxS, off);
        if (oL > bestL || (oL == bestL && oiL < idxL)) { bestL = oL; idxL = oiL; }
        if (oS > bestS || (oS == bestS && oiS < idxS)) { bestS = oS; idxS = oiS; }
    }
    if (lane == 0) {
        int ia = inv_table[idxS];    // inv_table[0] == 0  <=>  scale argmax hit 0
        gtable[p] = (uint32_t)idxL | ((uint32_t)ia << 16);
    }
}

// K2: fused extract + speculative chunk functions. One block per (batch, chunk).
// Streams its own 32 x-rows (32.9 KB), finds hot indices, then runs the 258
// 32-step chains for this chunk. Chain VALU/LDS work hides under the grid-wide
// memory stream. Writes f row (258 u16) and xs (32 u16).
__global__ void __launch_bounds__(256)
extract_chunks(const uint32_t* __restrict__ gtable, const f32x4* __restrict__ x4,
               uint16_t* __restrict__ xidx, uint16_t* __restrict__ f) {
    __shared__ uint32_t tbl[NSTATE];
    __shared__ uint16_t xs[CLEN];
    int b = blockIdx.x >> 5, c = blockIdx.x & 31;
    int tid = threadIdx.x;

    for (int j = tid; j < NSTATE; j += 256) tbl[j] = gtable[j];

    // stream this chunk's x slice: 2056 f32x4, element base local to the chunk
    const f32x4* xbase = x4 + ((size_t)(b * L + c * CLEN) * V) / 4;
    for (int i = tid; i < VECS_PER_CHUNK; i += 256) {
        f32x4 v = xbase[i];
        int e = i * 4;                                  // local element index
        if (v.x == 1.0f) { int r = e / V;       xs[r] = (uint16_t)(e     - r * V); }
        if (v.y == 1.0f) { int r = (e + 1) / V; xs[r] = (uint16_t)(e + 1 - r * V); }
        if (v.z == 1.0f) { int r = (e + 2) / V; xs[r] = (uint16_t)(e + 2 - r * V); }
        if (v.w == 1.0f) { int r = (e + 3) / V; xs[r] = (uint16_t)(e + 3 - r * V); }
    }
    __syncthreads();

    // 258 speculative chains: states tid, plus 256+tid for tid<2
    int p0 = tid;
    int p1 = (tid < 2) ? tid + 256 : 0;   // dummy chain for tid >= 2
    #pragma unroll 4
    for (int k = 0; k < CLEN; ++k) {
        int x = xs[k];
        p0 = gstep(tbl, p0, x);
        p1 = gstep(tbl, p1, x);
    }
    uint16_t* frow = f + (size_t)blockIdx.x * NSTATE;
    frow[tid] = (uint16_t)p0;
    if (tid < 2) frow[tid + 256] = (uint16_t)p1;
    if (tid < CLEN) xidx[b * L + c * CLEN + tid] = xs[tid];
}

// K3: fused compose + replay + one-hot store. One block per (batch, chunk).
// Loads the batch's chunk maps 0..c-1 (<=16 KB), hops to this chunk's entry state,
// replays its 32 steps, then streams the chunk's 131.6 KB of one-hot output.
__global__ void __launch_bounds__(256)
replay_write(const uint32_t* __restrict__ gtable, const uint16_t* __restrict__ xidx,
             const uint16_t* __restrict__ f, f32x4* __restrict__ out) {
    __shared__ uint32_t tbl[NSTATE];
    __shared__ uint16_t fl[(CHUNKS - 1) * NSTATE];   // rows 0..c-1 (max 31)
    __shared__ uint16_t xs[CLEN];
    __shared__ uint16_t os[CLEN];
    int b = blockIdx.x >> 5, c = blockIdx.x & 31;
    int tid = threadIdx.x;

    for (int j = tid; j < NSTATE; j += 256) tbl[j] = gtable[j];
    int nfl = c * NSTATE;
    const uint16_t* fb = f + (size_t)b * CHUNKS * NSTATE;
    for (int j = tid; j < nfl; j += 256) fl[j] = fb[j];
    if (tid < CLEN) xs[tid] = xidx[b * L + c * CLEN + tid];
    __syncthreads();

    if (tid == 0) {
        int st = ZERO_STATE;
        for (int i = 0; i < c; ++i) st = fl[i * NSTATE + st];   // entry state of chunk c
        int p = st;
        for (int k = 0; k < CLEN; ++k) {                         // replay this chunk
            int x = xs[k];
            uint32_t e = tbl[p];
            int ia  = (int)(e >> 16);
            int loc = (int)(e & 0xffff);
            if (ia == 0) {
                os[k] = 0xFFFF;          // zero-vector row
                p = ZERO_STATE;
            } else {
                int s = x - loc;
                s += (s >> 31) & V;
                int n = s * ia;
                int m = (n & 255) - (n >> 8);
                m += (m >> 31) & V;
                os[k] = (uint16_t)m;
                p = m;
            }
        }
    }
    __syncthreads();

    // stream the chunk's 2056 f32x4 vectors; elements span at most 2 rows each.
    f32x4* obase = out + ((size_t)(b * L + c * CLEN) * V) / 4;
    for (int i = tid; i < VECS_PER_CHUNK; i += 256) {
        int e = i * 4;
        int r = e / V;
        int col = e - r * V;
        int h0 = os[r];
        int h1 = (col + 3 >= V) ? os[r + 1] : h0;   // wrap stays within the chunk
        f32x4 v;
        int cc = col;
        v.x = (cc == h0) ? 1.0f : 0.0f; cc++;
        if (cc == V) { cc = 0; h0 = h1; }
        v.y = (cc == h0) ? 1.0f : 0.0f; cc++;
        if (cc == V) { cc = 0; h0 = h1; }
        v.z = (cc == h0) ? 1.0f : 0.0f; cc++;
        if (cc == V) { cc = 0; h0 = h1; }
        v.w = (cc == h0) ? 1.0f : 0.0f;
        obase[i] = v;
    }
}

extern "C" void kernel_launch(void* const* d_in, const int* in_sizes, int n_in,
                              void* d_out, int out_size, void* d_ws, size_t ws_size,
                              hipStream_t stream) {
    const float* x    = (const float*)d_in[0];   // [B, L, V] one-hot f32
    const float* W    = (const float*)d_in[1];   // [V, 2V]
    const float* bias = (const float*)d_in[2];   // [2V]
    const int*   inv  = (const int*)d_in[3];     // [V]

    uint8_t* ws = (uint8_t*)d_ws;
    uint32_t* gtable = (uint32_t*)ws;                           // 258*4 B (4 KB slot)
    uint16_t* xidx   = (uint16_t*)(ws + 4096);                  // 128 KB
    uint16_t* f      = (uint16_t*)(ws + 4096 + NB * L * 2);     // 2048*258*2 ~ 1.06 MB

    table_k<<<NSTATE, 64, 0, stream>>>(W, bias, inv, gtable);
    extract_chunks<<<NB * CHUNKS, 256, 0, stream>>>(gtable, (const f32x4*)x, xidx, f);
    replay_write<<<NB * CHUNKS, 256, 0, stream>>>(gtable, xidx, f, (f32x4*)d_out);
}

// Round 9
// 138.339 us; speedup vs baseline: 1.0242x; 1.0242x over previous
//
#include <hip/hip_runtime.h>
#include <stdint.h>

#define V 257
#define NB 64
#define L 1024
#define ZERO_STATE 257   // table slot for the all-zero prev vector
#define NSTATE 258
#define CHUNKS 32        // C
#define CLEN 32          // K ; C*K == L
#define EXTRACT_BLOCKS 2048
#define VECS_PER_CHUNK 2056   // 32*257/4, exact; chunk base is f32x4-aligned

typedef float f32x4 __attribute__((ext_vector_type(4)));

// transition: state p + input index x -> next state (== output index;
// ZERO_STATE means "output is the all-zero vector").
__device__ __forceinline__ int gstep(const uint32_t* __restrict__ tbl, int p, int x) {
    uint32_t e = tbl[p];
    int ia  = (int)(e >> 16);
    int loc = (int)(e & 0xffff);
    int s = x - loc;               // (-257, 257)
    s += (s >> 31) & V;            // mod V -> [0,256]
    int n = s * ia;                // <= 65536
    int m = (n & 255) - (n >> 8);  // 256 == -1 (mod 257) fold -> [-256,255]
    m += (m >> 31) & V;            // -> [0,256]
    return (ia == 0) ? ZERO_STATE : m;
}

// K1: fused. Blocks 0..257: per-state transition table (entry = loc | ia<<16,
// ia==0 encodes zero-vector output). Blocks 258+: extract one-hot index per (b,t).
// Plain cached loads: the harness's input-restore copy leaves x hot in L3
// (R5 showed nontemporal loads here cost ~8 us).
__global__ void prep(const float* __restrict__ W, const float* __restrict__ bias,
                     const int* __restrict__ inv_table, const f32x4* __restrict__ x4,
                     uint32_t* __restrict__ gtable, uint16_t* __restrict__ xidx, int n4) {
    if (blockIdx.x < NSTATE) {
        int lane = threadIdx.x;
        if (lane >= 64) return;          // one wave does the row
        int p = blockIdx.x;              // 257 = zero state (net = bias only)
        const float* wrow = (p < V) ? (W + (size_t)p * (2 * V)) : nullptr;
        float bestL = -INFINITY; int idxL = 0;
        float bestS = -INFINITY; int idxS = 0;
        for (int j = lane; j < V; j += 64) {
            float vl = wrow ? (wrow[j] + bias[j]) : bias[j];
            float vs = wrow ? (wrow[V + j] + bias[V + j]) : bias[V + j];
            if (vl > bestL) { bestL = vl; idxL = j; }   // ascending j => first-max kept
            if (vs > bestS) { bestS = vs; idxS = j; }
        }
        for (int off = 32; off >= 1; off >>= 1) {       // wave-64 first-index argmax reduce
            float oL = __shfl_down(bestL, off); int oiL = __shfl_down(idxL, off);
            float oS = __shfl_down(bestS, off); int oiS = __shfl_down(idxS, off);
            if (oL > bestL || (oL == bestL && oiL < idxL)) { bestL = oL; idxL = oiL; }
            if (oS > bestS || (oS == bestS && oiS < idxS)) { bestS = oS; idxS = oiS; }
        }
        if (lane == 0) {
            int ia = inv_table[idxS];    // inv_table[0] == 0  <=>  scale argmax hit 0
            gtable[p] = (uint32_t)idxL | ((uint32_t)ia << 16);
        }
        return;
    }
    int stride = EXTRACT_BLOCKS * blockDim.x;
    for (int i = (blockIdx.x - NSTATE) * blockDim.x + threadIdx.x; i < n4; i += stride) {
        f32x4 v = x4[i];
        int j = i * 4;
        if (v.x == 1.0f) { int r = j / V;       xidx[r] = (uint16_t)(j     - r * V); }
        if (v.y == 1.0f) { int r = (j + 1) / V; xidx[r] = (uint16_t)(j + 1 - r * V); }
        if (v.z == 1.0f) { int r = (j + 2) / V; xidx[r] = (uint16_t)(j + 2 - r * V); }
        if (v.w == 1.0f) { int r = (j + 3) / V; xidx[r] = (uint16_t)(j + 3 - r * V); }
    }
}

// K2: speculative chunk functions, standalone (R8 showed fusing this into the
// x-streaming blocks serializes the chain tail behind each block's stream).
// One block per (batch, chunk); 128 threads x 3 chains cover all 258 states.
__global__ void phase1(const uint32_t* __restrict__ gtable, const uint16_t* __restrict__ xidx,
                       uint16_t* __restrict__ f) {
    __shared__ uint32_t tbl[NSTATE];
    __shared__ uint16_t xs[CLEN];
    int bc = blockIdx.x;
    int b = bc / CHUNKS, c = bc % CHUNKS;
    int tid = threadIdx.x;
    for (int j = tid; j < NSTATE; j += 128) tbl[j] = gtable[j];
    if (tid < CLEN) xs[tid] = xidx[b * L + c * CLEN + tid];
    __syncthreads();
    int p0 = tid;
    int p1 = tid + 128;
    int p2 = (tid + 256 < NSTATE) ? tid + 256 : 0;   // dummy chain for tid >= 2
    #pragma unroll 4
    for (int k = 0; k < CLEN; ++k) {
        int x = xs[k];
        p0 = gstep(tbl, p0, x);
        p1 = gstep(tbl, p1, x);
        p2 = gstep(tbl, p2, x);
    }
    uint16_t* frow = f + (size_t)bc * NSTATE;
    frow[tid] = (uint16_t)p0;
    frow[tid + 128] = (uint16_t)p1;
    if (tid < 2) frow[tid + 256] = (uint16_t)p2;
}

// K3: fused compose + replay + one-hot store. One block per (batch, chunk).
// Loads the batch's chunk maps 0..c-1 (<=16 KB), hops to this chunk's entry state,
// replays its 32 steps, then streams the chunk's 131.6 KB of one-hot output.
__global__ void __launch_bounds__(256)
replay_write(const uint32_t* __restrict__ gtable, const uint16_t* __restrict__ xidx,
             const uint16_t* __restrict__ f, f32x4* __restrict__ out) {
    __shared__ uint32_t tbl[NSTATE];
    __shared__ uint16_t fl[(CHUNKS - 1) * NSTATE];   // rows 0..c-1 (max 31)
    __shared__ uint16_t xs[CLEN];
    __shared__ uint16_t os[CLEN];
    int b = blockIdx.x >> 5, c = blockIdx.x & 31;
    int tid = threadIdx.x;

    for (int j = tid; j < NSTATE; j += 256) tbl[j] = gtable[j];
    int nfl = c * NSTATE;
    const uint16_t* fb = f + (size_t)b * CHUNKS * NSTATE;
    for (int j = tid; j < nfl; j += 256) fl[j] = fb[j];
    if (tid < CLEN) xs[tid] = xidx[b * L + c * CLEN + tid];
    __syncthreads();

    if (tid == 0) {
        int st = ZERO_STATE;
        for (int i = 0; i < c; ++i) st = fl[i * NSTATE + st];   // entry state of chunk c
        int p = st;
        for (int k = 0; k < CLEN; ++k) {                         // replay this chunk
            int x = xs[k];
            uint32_t e = tbl[p];
            int ia  = (int)(e >> 16);
            int loc = (int)(e & 0xffff);
            if (ia == 0) {
                os[k] = 0xFFFF;          // zero-vector row
                p = ZERO_STATE;
            } else {
                int s = x - loc;
                s += (s >> 31) & V;
                int n = s * ia;
                int m = (n & 255) - (n >> 8);
                m += (m >> 31) & V;
                os[k] = (uint16_t)m;
                p = m;
            }
        }
    }
    __syncthreads();

    // stream the chunk's 2056 f32x4 vectors; elements span at most 2 rows each.
    f32x4* obase = out + ((size_t)(b * L + c * CLEN) * V) / 4;
    for (int i = tid; i < VECS_PER_CHUNK; i += 256) {
        int e = i * 4;
        int r = e / V;
        int col = e - r * V;
        int h0 = os[r];
        int h1 = (col + 3 >= V) ? os[r + 1] : h0;   // wrap stays within the chunk
        f32x4 v;
        int cc = col;
        v.x = (cc == h0) ? 1.0f : 0.0f; cc++;
        if (cc == V) { cc = 0; h0 = h1; }
        v.y = (cc == h0) ? 1.0f : 0.0f; cc++;
        if (cc == V) { cc = 0; h0 = h1; }
        v.z = (cc == h0) ? 1.0f : 0.0f; cc++;
        if (cc == V) { cc = 0; h0 = h1; }
        v.w = (cc == h0) ? 1.0f : 0.0f;
        obase[i] = v;
    }
}

extern "C" void kernel_launch(void* const* d_in, const int* in_sizes, int n_in,
                              void* d_out, int out_size, void* d_ws, size_t ws_size,
                              hipStream_t stream) {
    const float* x    = (const float*)d_in[0];   // [B, L, V] one-hot f32
    const float* W    = (const float*)d_in[1];   // [V, 2V]
    const float* bias = (const float*)d_in[2];   // [2V]
    const int*   inv  = (const int*)d_in[3];     // [V]

    uint8_t* ws = (uint8_t*)d_ws;
    uint32_t* gtable = (uint32_t*)ws;                           // 258*4 B (4 KB slot)
    uint16_t* xidx   = (uint16_t*)(ws + 4096);                  // 128 KB
    uint16_t* f      = (uint16_t*)(ws + 4096 + NB * L * 2);     // 2048*258*2 ~ 1.06 MB

    int n4 = NB * L * V / 4;   // 4,210,688 exact

    prep<<<NSTATE + EXTRACT_BLOCKS, 256, 0, stream>>>(W, bias, inv, (const f32x4*)x,
                                                      gtable, xidx, n4);
    phase1<<<NB * CHUNKS, 128, 0, stream>>>(gtable, xidx, f);
    replay_write<<<NB * CHUNKS, 256, 0, stream>>>(gtable, xidx, f, (f32x4*)d_out);
}